// Round 1
// baseline (1624.295 us; speedup 1.0000x reference)
//
#include <hip/hip_runtime.h>
#include <hip/hip_bf16.h>
#include <math.h>

// ---------------------------------------------------------------------------
// Swin-style shifted-window transformer block, MI355X (gfx950).
// Key insight: the "motion bias" mb is constant along the softmax (key) axis
// -> softmax-invariant -> flow branch skipped entirely.
// bf16 MFMA (16x16x32) everywhere, fp32 accumulate. fp32 in/out.
// ---------------------------------------------------------------------------

typedef unsigned short u16;
typedef unsigned int   u32;
typedef __bf16 bf16_t;
typedef bf16_t bf16x8 __attribute__((ext_vector_type(8)));
typedef float  f32x4  __attribute__((ext_vector_type(4)));

#define HIMG 256
#define WIMG 256
#define CCH  256
#define HEADS 8
#define HD 32
#define SHIFTV 4
#define MLP_HID 1024

#define MFMA(a,b,c) __builtin_amdgcn_mfma_f32_16x16x32_bf16((a),(b),(c),0,0,0)

__device__ __forceinline__ u16 f2bf(float f) {
  union { float f; u32 u; } c; c.f = f;
  u32 u = c.u;
  return (u16)((u + 0x7FFFu + ((u >> 16) & 1u)) >> 16);
}

// ---------------- weight prep: fp32 -> bf16, transposed [N][K] --------------
// layout in ws (u16 units):
//   qkvT : [768][256]  at 0
//   projT: [256][256]  at 196608
//   w1T  : [1024][256] at 262144
//   w2T  : [256][1024] at 524288
__global__ void prep_weights(const float* __restrict__ qkv_w,
                             const float* __restrict__ proj_w,
                             const float* __restrict__ w1,
                             const float* __restrict__ w2,
                             u16* __restrict__ out)
{
  int idx = blockIdx.x * 256 + threadIdx.x;
  if (idx < 768 * 256) {
    int n = idx >> 8, k = idx & 255;
    out[idx] = f2bf(qkv_w[k * 768 + n]);
    return;
  }
  idx -= 768 * 256;
  if (idx < 256 * 256) {
    int n = idx >> 8, k = idx & 255;
    out[768 * 256 + idx] = f2bf(proj_w[k * 256 + n]);
    return;
  }
  idx -= 256 * 256;
  if (idx < 1024 * 256) {
    int n = idx >> 8, k = idx & 255;
    out[768 * 256 + 256 * 256 + idx] = f2bf(w1[k * 1024 + n]);
    return;
  }
  idx -= 1024 * 256;
  {
    int n = idx >> 10, k = idx & 1023;
    out[768 * 256 + 256 * 256 + 1024 * 256 + idx] = f2bf(w2[k * 256 + n]);
  }
}

// ---------------- fused LN1 + window attention + proj + residual ------------
// grid = 4096 windows, block = 512 (8 waves, one head per wave)
__global__ __launch_bounds__(512)
void attn_kernel(const float* __restrict__ x,
                 const float* __restrict__ qkv_b,
                 const float* __restrict__ proj_b,
                 const float* __restrict__ n1g,
                 const float* __restrict__ n1b,
                 const u16*  __restrict__ wbuf,
                 float* __restrict__ xmid)
{
  const u16* qkvT  = wbuf;               // [768][256]
  const u16* projT = wbuf + 768 * 256;   // [256][256]

  __shared__ __align__(16) u16 x_lds[64 * 264];        // xw tile; later out tile
  __shared__ __align__(16) u16 qk_lds[8][2 * 64 * 40]; // per head: q | k ; P overlays
  __shared__ __align__(16) u16 vt_lds[8][32 * 72];     // per head: V^T

  const int tid  = threadIdx.x;
  const int lane = tid & 63;
  const int wid  = tid >> 6;      // head
  const int l15  = lane & 15;
  const int g4   = lane >> 4;

  const int w  = blockIdx.x;
  const int bb = w >> 10;
  const int wy = (w >> 5) & 31;
  const int wx = w & 31;

  // ---- phase 0: gather (shifted) rows + LN1 -> x_lds bf16 ----
  {
    const int r  = tid >> 3;       // token 0..63
    const int l8 = tid & 7;
    const int ty = r >> 3, tx = r & 7;
    const int py = (wy * 8 + ty + SHIFTV) & 255;
    const int px = (wx * 8 + tx + SHIFTV) & 255;
    const float* src = x + ((((size_t)bb * HIMG + py) * WIMG + px) * CCH) + l8 * 32;
    float v[32];
    float s = 0.f, ss = 0.f;
#pragma unroll
    for (int j = 0; j < 8; ++j) {
      float4 f = *(const float4*)(src + j * 4);
      v[4*j+0] = f.x; v[4*j+1] = f.y; v[4*j+2] = f.z; v[4*j+3] = f.w;
      s  += f.x + f.y + f.z + f.w;
      ss += f.x*f.x + f.y*f.y + f.z*f.z + f.w*f.w;
    }
#pragma unroll
    for (int m = 1; m <= 4; m <<= 1) {
      s  += __shfl_xor(s, m);
      ss += __shfl_xor(ss, m);
    }
    const float mean = s * (1.f / 256.f);
    const float var  = ss * (1.f / 256.f) - mean * mean;
    const float rstd = rsqrtf(var + 1e-5f);
    const float* gp = n1g + l8 * 32;
    const float* bp = n1b + l8 * 32;
    u16* dst = &x_lds[r * 264 + l8 * 32];
#pragma unroll
    for (int j = 0; j < 32; ++j)
      dst[j] = f2bf((v[j] - mean) * rstd * gp[j] + bp[j]);
  }
  __syncthreads();

  // ---- phase 1: QKV for this head (q,k,v each 64x32) ----
  f32x4 qa[4][2], ka[4][2], va[4][2];
#pragma unroll
  for (int i = 0; i < 4; ++i)
#pragma unroll
    for (int j = 0; j < 2; ++j) {
      qa[i][j] = (f32x4){0.f,0.f,0.f,0.f};
      ka[i][j] = (f32x4){0.f,0.f,0.f,0.f};
      va[i][j] = (f32x4){0.f,0.f,0.f,0.f};
    }

#pragma unroll
  for (int kk = 0; kk < 8; ++kk) {
    bf16x8 af[4];
#pragma unroll
    for (int i = 0; i < 4; ++i)
      af[i] = *(const bf16x8*)&x_lds[(i * 16 + l15) * 264 + kk * 32 + g4 * 8];
#pragma unroll
    for (int j = 0; j < 2; ++j) {
      const int colq = wid * 32 + j * 16 + l15;
      bf16x8 bq = *(const bf16x8*)&qkvT[(size_t)(colq      ) * 256 + kk * 32 + g4 * 8];
      bf16x8 bk = *(const bf16x8*)&qkvT[(size_t)(colq + 256) * 256 + kk * 32 + g4 * 8];
      bf16x8 bv = *(const bf16x8*)&qkvT[(size_t)(colq + 512) * 256 + kk * 32 + g4 * 8];
#pragma unroll
      for (int i = 0; i < 4; ++i) {
        qa[i][j] = MFMA(af[i], bq, qa[i][j]);
        ka[i][j] = MFMA(af[i], bk, ka[i][j]);
        va[i][j] = MFMA(af[i], bv, va[i][j]);
      }
    }
  }

  u16* qbuf = &qk_lds[wid][0];
  u16* kbuf = &qk_lds[wid][64 * 40];
  u16* vtb  = &vt_lds[wid][0];
  const float scale = 0.17677669529663687f;  // 32^-0.5
#pragma unroll
  for (int i = 0; i < 4; ++i)
#pragma unroll
    for (int j = 0; j < 2; ++j) {
      const int colL = j * 16 + l15;
      const int colG = wid * 32 + colL;
      const float bq_ = qkv_b[colG];
      const float bk_ = qkv_b[256 + colG];
      const float bv_ = qkv_b[512 + colG];
#pragma unroll
      for (int r = 0; r < 4; ++r) {
        const int row = i * 16 + g4 * 4 + r;
        qbuf[row * 40 + colL] = f2bf((qa[i][j][r] + bq_) * scale);
        kbuf[row * 40 + colL] = f2bf(ka[i][j][r] + bk_);
        vtb[colL * 72 + row]  = f2bf(va[i][j][r] + bv_);
      }
    }

  // ---- phase 2: S = Qs @ K^T  (K=32 -> one MFMA per 16x16 tile) ----
  f32x4 sacc[4][4];
#pragma unroll
  for (int i = 0; i < 4; ++i)
#pragma unroll
    for (int j = 0; j < 4; ++j) sacc[i][j] = (f32x4){0.f,0.f,0.f,0.f};
  {
    bf16x8 aq[4], bk4[4];
#pragma unroll
    for (int i = 0; i < 4; ++i) aq[i]  = *(const bf16x8*)&qbuf[(i * 16 + l15) * 40 + g4 * 8];
#pragma unroll
    for (int j = 0; j < 4; ++j) bk4[j] = *(const bf16x8*)&kbuf[(j * 16 + l15) * 40 + g4 * 8];
#pragma unroll
    for (int i = 0; i < 4; ++i)
#pragma unroll
      for (int j = 0; j < 4; ++j) sacc[i][j] = MFMA(aq[i], bk4[j], sacc[i][j]);
  }

  // ---- phase 3: softmax (rows held by 16-lane groups) -> P bf16 (overlay) --
  u16* pbuf = &qk_lds[wid][0];   // overlays q|k (dead now); stride 72
#pragma unroll
  for (int i = 0; i < 4; ++i) {
#pragma unroll
    for (int r = 0; r < 4; ++r) {
      float mx = -1e30f;
#pragma unroll
      for (int j = 0; j < 4; ++j) mx = fmaxf(mx, sacc[i][j][r]);
#pragma unroll
      for (int m = 1; m <= 8; m <<= 1) mx = fmaxf(mx, __shfl_xor(mx, m));
      float pv[4]; float sum = 0.f;
#pragma unroll
      for (int j = 0; j < 4; ++j) { pv[j] = expf(sacc[i][j][r] - mx); sum += pv[j]; }
#pragma unroll
      for (int m = 1; m <= 8; m <<= 1) sum += __shfl_xor(sum, m);
      const float inv = 1.f / sum;
      const int row = i * 16 + g4 * 4 + r;
#pragma unroll
      for (int j = 0; j < 4; ++j)
        pbuf[row * 72 + j * 16 + l15] = f2bf(pv[j] * inv);
    }
  }

  // ---- phase 4: O = P @ V ----
  f32x4 oacc[4][2];
#pragma unroll
  for (int i = 0; i < 4; ++i)
#pragma unroll
    for (int j = 0; j < 2; ++j) oacc[i][j] = (f32x4){0.f,0.f,0.f,0.f};
#pragma unroll
  for (int kk = 0; kk < 2; ++kk) {
    bf16x8 ap[4];
#pragma unroll
    for (int i = 0; i < 4; ++i)
      ap[i] = *(const bf16x8*)&pbuf[(i * 16 + l15) * 72 + kk * 32 + g4 * 8];
#pragma unroll
    for (int j = 0; j < 2; ++j) {
      bf16x8 bv = *(const bf16x8*)&vtb[(j * 16 + l15) * 72 + kk * 32 + g4 * 8];
#pragma unroll
      for (int i = 0; i < 4; ++i) oacc[i][j] = MFMA(ap[i], bv, oacc[i][j]);
    }
  }

  // ---- phase 5: O -> out tile in x_lds (xw dead for all waves now) ----
  __syncthreads();
#pragma unroll
  for (int i = 0; i < 4; ++i)
#pragma unroll
    for (int j = 0; j < 2; ++j)
#pragma unroll
      for (int r = 0; r < 4; ++r) {
        const int row = i * 16 + g4 * 4 + r;
        const int col = wid * 32 + j * 16 + l15;
        x_lds[row * 264 + col] = f2bf(oacc[i][j][r]);
      }
  __syncthreads();

  // ---- phase 6: proj + shortcut + write x_mid ----
  f32x4 pacc[4][2];
#pragma unroll
  for (int i = 0; i < 4; ++i)
#pragma unroll
    for (int j = 0; j < 2; ++j) pacc[i][j] = (f32x4){0.f,0.f,0.f,0.f};
#pragma unroll
  for (int kk = 0; kk < 8; ++kk) {
    bf16x8 af[4];
#pragma unroll
    for (int i = 0; i < 4; ++i)
      af[i] = *(const bf16x8*)&x_lds[(i * 16 + l15) * 264 + kk * 32 + g4 * 8];
#pragma unroll
    for (int j = 0; j < 2; ++j) {
      bf16x8 bw = *(const bf16x8*)&projT[(size_t)(wid * 32 + j * 16 + l15) * 256 + kk * 32 + g4 * 8];
#pragma unroll
      for (int i = 0; i < 4; ++i) pacc[i][j] = MFMA(af[i], bw, pacc[i][j]);
    }
  }
#pragma unroll
  for (int i = 0; i < 4; ++i)
#pragma unroll
    for (int j = 0; j < 2; ++j) {
      const int col = wid * 32 + j * 16 + l15;
      const float pb = proj_b[col];
#pragma unroll
      for (int r = 0; r < 4; ++r) {
        const int row = i * 16 + g4 * 4 + r;
        const int ty = row >> 3, tx = row & 7;
        const int py = (wy * 8 + ty + SHIFTV) & 255;
        const int px = (wx * 8 + tx + SHIFTV) & 255;
        const size_t off = (((size_t)bb * HIMG + py) * WIMG + px) * CCH + col;
        xmid[off] = x[off] + pacc[i][j][r] + pb;
      }
    }
}

// ---------------- fused LN2 + MLP (GELU exact) + residual, in-place ---------
// grid = 4096 x 64-row tiles, block = 512 (8 waves)
__global__ __launch_bounds__(512)
void mlp_kernel(const float* __restrict__ b1,
                const float* __restrict__ b2,
                const float* __restrict__ n2g,
                const float* __restrict__ n2b,
                const u16*  __restrict__ wbuf,
                float* __restrict__ xio)
{
  const u16* w1T = wbuf + 768 * 256 + 256 * 256;              // [1024][256]
  const u16* w2T = wbuf + 768 * 256 + 256 * 256 + 1024 * 256; // [256][1024]

  __shared__ __align__(16) u16 x_lds[64 * 264];
  __shared__ __align__(16) u16 h_lds[64 * 520];

  const int tid  = threadIdx.x;
  const int lane = tid & 63;
  const int wid  = tid >> 6;
  const int l15  = lane & 15;
  const int g4   = lane >> 4;
  const size_t row0 = (size_t)blockIdx.x * 64;

  // ---- phase 0: LN2 -> x_lds bf16 ----
  {
    const int r  = tid >> 3;
    const int l8 = tid & 7;
    const float* src = xio + (row0 + r) * 256 + l8 * 32;
    float v[32];
    float s = 0.f, ss = 0.f;
#pragma unroll
    for (int j = 0; j < 8; ++j) {
      float4 f = *(const float4*)(src + j * 4);
      v[4*j+0] = f.x; v[4*j+1] = f.y; v[4*j+2] = f.z; v[4*j+3] = f.w;
      s  += f.x + f.y + f.z + f.w;
      ss += f.x*f.x + f.y*f.y + f.z*f.z + f.w*f.w;
    }
#pragma unroll
    for (int m = 1; m <= 4; m <<= 1) {
      s  += __shfl_xor(s, m);
      ss += __shfl_xor(ss, m);
    }
    const float mean = s * (1.f / 256.f);
    const float var  = ss * (1.f / 256.f) - mean * mean;
    const float rstd = rsqrtf(var + 1e-5f);
    const float* gp = n2g + l8 * 32;
    const float* bp = n2b + l8 * 32;
    u16* dst = &x_lds[r * 264 + l8 * 32];
#pragma unroll
    for (int j = 0; j < 32; ++j)
      dst[j] = f2bf((v[j] - mean) * rstd * gp[j] + bp[j]);
  }
  __syncthreads();

  f32x4 oacc[4][2];
#pragma unroll
  for (int i = 0; i < 4; ++i)
#pragma unroll
    for (int j = 0; j < 2; ++j) oacc[i][j] = (f32x4){0.f,0.f,0.f,0.f};

  for (int half = 0; half < 2; ++half) {
    // G1: hidden slice [64, 64] per wave (this half's 512 cols / 8 waves)
    f32x4 hacc[4][4];
#pragma unroll
    for (int i = 0; i < 4; ++i)
#pragma unroll
      for (int j = 0; j < 4; ++j) hacc[i][j] = (f32x4){0.f,0.f,0.f,0.f};
#pragma unroll
    for (int kk = 0; kk < 8; ++kk) {
      bf16x8 af[4];
#pragma unroll
      for (int i = 0; i < 4; ++i)
        af[i] = *(const bf16x8*)&x_lds[(i * 16 + l15) * 264 + kk * 32 + g4 * 8];
#pragma unroll
      for (int j = 0; j < 4; ++j) {
        bf16x8 bw = *(const bf16x8*)&w1T[(size_t)(half * 512 + wid * 64 + j * 16 + l15) * 256 + kk * 32 + g4 * 8];
#pragma unroll
        for (int i = 0; i < 4; ++i) hacc[i][j] = MFMA(af[i], bw, hacc[i][j]);
      }
    }
    if (half) __syncthreads();   // prev-half G2 readers must finish before overwrite
    // GELU(exact) + bias -> h_lds bf16
#pragma unroll
    for (int i = 0; i < 4; ++i)
#pragma unroll
      for (int j = 0; j < 4; ++j) {
        const int colL = wid * 64 + j * 16 + l15;
        const float b1v = b1[half * 512 + colL];
#pragma unroll
        for (int r = 0; r < 4; ++r) {
          const int row = i * 16 + g4 * 4 + r;
          const float vv = hacc[i][j][r] + b1v;
          const float ge = 0.5f * vv * (1.f + erff(vv * 0.70710678118654752f));
          h_lds[row * 520 + colL] = f2bf(ge);
        }
      }
    __syncthreads();
    // G2: out slice [64, 32] per wave, accumulate across halves
#pragma unroll
    for (int kk = 0; kk < 16; ++kk) {
      bf16x8 ah[4];
#pragma unroll
      for (int i = 0; i < 4; ++i)
        ah[i] = *(const bf16x8*)&h_lds[(i * 16 + l15) * 520 + kk * 32 + g4 * 8];
#pragma unroll
      for (int j = 0; j < 2; ++j) {
        bf16x8 bw = *(const bf16x8*)&w2T[(size_t)(wid * 32 + j * 16 + l15) * 1024 + half * 512 + kk * 32 + g4 * 8];
#pragma unroll
        for (int i = 0; i < 4; ++i) oacc[i][j] = MFMA(ah[i], bw, oacc[i][j]);
      }
    }
  }

  // ---- epilogue: + bias + residual, in-place write ----
#pragma unroll
  for (int i = 0; i < 4; ++i)
#pragma unroll
    for (int j = 0; j < 2; ++j) {
      const int col = wid * 32 + j * 16 + l15;
      const float b2v = b2[col];
#pragma unroll
      for (int r = 0; r < 4; ++r) {
        const int row = i * 16 + g4 * 4 + r;
        const size_t off = (row0 + row) * 256 + col;
        xio[off] = xio[off] + oacc[i][j][r] + b2v;
      }
    }
}

// ---------------------------------------------------------------------------
extern "C" void kernel_launch(void* const* d_in, const int* in_sizes, int n_in,
                              void* d_out, int out_size, void* d_ws, size_t ws_size,
                              hipStream_t stream)
{
  const float* x      = (const float*)d_in[0];
  // d_in[1] = flow  (unused: motion bias is softmax-invariant)
  const float* qkv_w  = (const float*)d_in[2];
  const float* qkv_b  = (const float*)d_in[3];
  const float* proj_w = (const float*)d_in[4];
  const float* proj_b = (const float*)d_in[5];
  // d_in[6..9] = off_* (unused)
  const float* n1g    = (const float*)d_in[10];
  const float* n1b    = (const float*)d_in[11];
  const float* n2g    = (const float*)d_in[12];
  const float* n2b    = (const float*)d_in[13];
  const float* w1     = (const float*)d_in[14];
  const float* b1     = (const float*)d_in[15];
  const float* w2     = (const float*)d_in[16];
  const float* b2     = (const float*)d_in[17];
  float* out = (float*)d_out;
  u16*   wbuf = (u16*)d_ws;   // 786432 u16 = 1.57 MB

  prep_weights<<<3072, 256, 0, stream>>>(qkv_w, proj_w, w1, w2, wbuf);
  attn_kernel<<<4096, 512, 0, stream>>>(x, qkv_b, proj_b, n1g, n1b, wbuf, out);
  mlp_kernel<<<4096, 512, 0, stream>>>(b1, b2, n2g, n2b, wbuf, out);
}